// Round 1
// baseline (672.656 us; speedup 1.0000x reference)
//
#include <hip/hip_runtime.h>
#include <hip/hip_bf16.h>

typedef unsigned short u16;
typedef __attribute__((ext_vector_type(8))) short bf16x8;   // 8 bf16 = 4 VGPRs (MFMA A/B frag)
typedef __attribute__((ext_vector_type(4))) float f32x4;    // MFMA C/D frag

// ---------- bf16 split helpers ----------
__device__ __forceinline__ u16 f2bf(float x) {
  union { float f; unsigned u; } v; v.f = x;
  unsigned r = v.u + 0x7fffu + ((v.u >> 16) & 1u);   // RNE
  return (u16)(r >> 16);
}
__device__ __forceinline__ float bf2f(u16 h) {
  union { unsigned u; float f; } v; v.u = ((unsigned)h) << 16; return v.f;
}

// async global->LDS, 16B per lane (dest must be wave-uniform base + lane*16)
__device__ __forceinline__ void gll16(const u16* g, u16* l) {
  __builtin_amdgcn_global_load_lds(
      (const __attribute__((address_space(1))) unsigned*)g,
      (__attribute__((address_space(3))) unsigned*)l, 16, 0, 0);
}

__device__ __forceinline__ f32x4 mfma_bb(bf16x8 a, bf16x8 b, f32x4 c) {
  return __builtin_amdgcn_mfma_f32_16x16x32_bf16(a, b, c, 0, 0, 0);
}

// ---------- prep: split inputs into hi/lo bf16 planes ----------
__global__ void prep_x(const float* __restrict__ x, u16* __restrict__ hi,
                       u16* __restrict__ lo, int n) {
  int i = blockIdx.x * 256 + threadIdx.x;
  if (i >= n) return;
  float v = x[i];
  u16 h = f2bf(v);
  hi[i] = h;
  lo[i] = f2bf(v - bf2f(h));
}

// ---------- prep: apply MADE mask + split weights ----------
// MODE 0: w0 [H,D]   mask = (row%127 >= col)          (m_in,  'input')
// MODE 1: w1 [H,H]   mask = (row%127 >= col%127)      (m_h)
// MODE 2: w2 [D,H]   mask = (row-1  >= col%127)       (m_out, 'output')
template <int MODE>
__global__ void prep_w(const float* __restrict__ w, u16* __restrict__ hi,
                       u16* __restrict__ lo, int rows, int cols) {
  int i = blockIdx.x * 256 + threadIdx.x;
  if (i >= rows * cols) return;
  int r = i / cols, c = i - r * cols;
  bool keep;
  if (MODE == 0)      keep = (r % 127) >= c;
  else if (MODE == 1) keep = (r % 127) >= (c % 127);
  else                keep = (r - 1) >= (c % 127);
  float v = keep ? w[i] : 0.0f;
  u16 h = f2bf(v);
  hi[i] = h;
  lo[i] = f2bf(v - bf2f(h));
}

// ---------- split-bf16 NT GEMM:  C[M,N] = (Ahi+Alo)[M,K] . (Bhi+Blo)[N,K]^T ----------
// 128x128 tile, 4 waves (2x2, each 64x64 = 4x4 frags of 16x16), BK=32.
// ACT 0: +bias, tanh, store split-bf16 h planes
// ACT 1: +bias, relu, store split-bf16 h planes
// ACT 2: no bias/act, store fp32 partial plane Cf + z*M*N (split-K over blockIdx.z)
template <int ACT>
__global__ __launch_bounds__(256, 2) void gemm_split(
    const u16* __restrict__ Ahi, const u16* __restrict__ Alo,
    const u16* __restrict__ Bhi, const u16* __restrict__ Blo,
    const float* __restrict__ bias,
    u16* __restrict__ Chi, u16* __restrict__ Clo,
    float* __restrict__ Cf,
    int M, int N, int K, int ksteps) {
  const int tid = threadIdx.x;
  const int l = tid & 63;
  const int w = tid >> 6;
  const int wr = w >> 1, wc = w & 1;
  const int bm = blockIdx.y * 128;
  const int bn = blockIdx.x * 128;
  const long kbase = (long)blockIdx.z * ksteps * 32;

  __shared__ __align__(16) u16 sAhi[4096];
  __shared__ __align__(16) u16 sAlo[4096];
  __shared__ __align__(16) u16 sBhi[4096];
  __shared__ __align__(16) u16 sBlo[4096];

  f32x4 acc[4][4] = {};

  // staging geometry: thread t copies 8 bf16 (16B): row = t>>2 (+64 for 2nd half), col = (t&3)*8
  const int srow = tid >> 2;
  const int scol = (tid & 3) << 3;
  const long aOff0 = (long)(bm + srow) * K + scol + kbase;
  const long aOff1 = aOff0 + 64L * K;
  const long bOff0 = (long)(bn + srow) * K + scol + kbase;
  const long bOff1 = bOff0 + 64L * K;
  const int ldst0 = tid * 8;
  const int ldst1 = 2048 + tid * 8;

  const int fr = l & 15, fq = l >> 4;

  for (int ks = 0; ks < ksteps; ++ks) {
    const long kk = (long)ks * 32;
    __syncthreads();
    gll16(Ahi + aOff0 + kk, sAhi + ldst0);
    gll16(Ahi + aOff1 + kk, sAhi + ldst1);
    gll16(Alo + aOff0 + kk, sAlo + ldst0);
    gll16(Alo + aOff1 + kk, sAlo + ldst1);
    gll16(Bhi + bOff0 + kk, sBhi + ldst0);
    gll16(Bhi + bOff1 + kk, sBhi + ldst1);
    gll16(Blo + bOff0 + kk, sBlo + ldst0);
    gll16(Blo + bOff1 + kk, sBlo + ldst1);
    __syncthreads();

    bf16x8 ah[4], alo[4], bh[4], blo[4];
#pragma unroll
    for (int m = 0; m < 4; ++m) {
      const int off = (wr * 64 + m * 16 + fr) * 32 + fq * 8;
      ah[m]  = *(const bf16x8*)(sAhi + off);
      alo[m] = *(const bf16x8*)(sAlo + off);
    }
#pragma unroll
    for (int n = 0; n < 4; ++n) {
      const int off = (wc * 64 + n * 16 + fr) * 32 + fq * 8;
      bh[n]  = *(const bf16x8*)(sBhi + off);
      blo[n] = *(const bf16x8*)(sBlo + off);
    }
#pragma unroll
    for (int m = 0; m < 4; ++m)
#pragma unroll
      for (int n = 0; n < 4; ++n) {
        acc[m][n] = mfma_bb(ah[m],  bh[n],  acc[m][n]);
        acc[m][n] = mfma_bb(alo[m], bh[n],  acc[m][n]);
        acc[m][n] = mfma_bb(ah[m],  blo[n], acc[m][n]);
      }
  }

  // epilogue; C/D layout: col = lane&15, row = (lane>>4)*4 + reg
  if (ACT == 2) {
    float* out = Cf + (long)blockIdx.z * M * N;
#pragma unroll
    for (int m = 0; m < 4; ++m) {
      const int row = bm + wr * 64 + m * 16 + fq * 4;
#pragma unroll
      for (int n = 0; n < 4; ++n) {
        const int col = bn + wc * 64 + n * 16 + fr;
#pragma unroll
        for (int r = 0; r < 4; ++r)
          out[(long)(row + r) * N + col] = acc[m][n][r];
      }
    }
  } else {
#pragma unroll
    for (int m = 0; m < 4; ++m) {
      const int row = bm + wr * 64 + m * 16 + fq * 4;
#pragma unroll
      for (int n = 0; n < 4; ++n) {
        const int col = bn + wc * 64 + n * 16 + fr;
        const float bv = bias[col];
#pragma unroll
        for (int r = 0; r < 4; ++r) {
          float z = acc[m][n][r] + bv;
          float h = (ACT == 0) ? tanhf(z) : fmaxf(z, 0.0f);
          u16 hi = f2bf(h);
          float rest = h - bf2f(hi);
          long idx = (long)(row + r) * N + col;
          Chi[idx] = hi;
          Clo[idx] = f2bf(rest);
        }
      }
    }
  }
}

// ---------- finalize: m = sum(pm)+s_b2, a = sum(pa)+t_b2, u=(x-m)exp(-a), -sum(a) ----------
__global__ void finalize_kernel(const float* __restrict__ x,
                                const float* __restrict__ pm,
                                const float* __restrict__ pa,
                                const float* __restrict__ sb2,
                                const float* __restrict__ tb2,
                                float* __restrict__ out_u,
                                float* __restrict__ out_s) {
  const int b = blockIdx.x * 4 + (threadIdx.x >> 6);
  const int l = threadIdx.x & 63;
  const long base = (long)b * 128;
  float m0 = sb2[l], m1 = sb2[64 + l];
  float a0 = tb2[l], a1 = tb2[64 + l];
#pragma unroll
  for (int k = 0; k < 4; ++k) {
    const long o = (long)k * (8192L * 128) + base;
    m0 += pm[o + l];      m1 += pm[o + 64 + l];
    a0 += pa[o + l];      a1 += pa[o + 64 + l];
  }
  out_u[base + l]      = (x[base + l]      - m0) * expf(-a0);
  out_u[base + 64 + l] = (x[base + 64 + l] - m1) * expf(-a1);
  float s = a0 + a1;
#pragma unroll
  for (int off = 32; off; off >>= 1) s += __shfl_down(s, off);
  if (l == 0) out_s[b] = -s;
}

extern "C" void kernel_launch(void* const* d_in, const int* in_sizes, int n_in,
                              void* d_out, int out_size, void* d_ws, size_t ws_size,
                              hipStream_t stream) {
  (void)in_sizes; (void)n_in; (void)out_size; (void)ws_size;
  const int B = 8192, D = 128, H = 2048;
  const float* x   = (const float*)d_in[0];
  const float* sw0 = (const float*)d_in[1];
  const float* sb0 = (const float*)d_in[2];
  const float* sw1 = (const float*)d_in[3];
  const float* sb1 = (const float*)d_in[4];
  const float* sw2 = (const float*)d_in[5];
  const float* sb2 = (const float*)d_in[6];
  const float* tw0 = (const float*)d_in[7];
  const float* tb0 = (const float*)d_in[8];
  const float* tw1 = (const float*)d_in[9];
  const float* tb1 = (const float*)d_in[10];
  const float* tw2 = (const float*)d_in[11];
  const float* tb2 = (const float*)d_in[12];

  // ---- workspace layout (~182 MB) ----
  char* ws = (char*)d_ws;
  size_t off = 0;
  auto alloc = [&](size_t bytes) {
    void* p = ws + off;
    off += (bytes + 255) & ~(size_t)255;
    return p;
  };
  u16* xhi  = (u16*)alloc((size_t)B * D * 2);
  u16* xlo  = (u16*)alloc((size_t)B * D * 2);
  u16* w0hi = (u16*)alloc((size_t)H * D * 2);
  u16* w0lo = (u16*)alloc((size_t)H * D * 2);
  u16* w1hi = (u16*)alloc((size_t)H * H * 2);
  u16* w1lo = (u16*)alloc((size_t)H * H * 2);
  u16* w2hi = (u16*)alloc((size_t)D * H * 2);
  u16* w2lo = (u16*)alloc((size_t)D * H * 2);
  u16* h1hi = (u16*)alloc((size_t)B * H * 2);
  u16* h1lo = (u16*)alloc((size_t)B * H * 2);
  u16* h2hi = (u16*)alloc((size_t)B * H * 2);
  u16* h2lo = (u16*)alloc((size_t)B * H * 2);
  float* pm = (float*)alloc((size_t)4 * B * D * 4);
  float* pa = (float*)alloc((size_t)4 * B * D * 4);

  float* out_u = (float*)d_out;
  float* out_s = out_u + (long)B * D;

  prep_x<<<(B * D + 255) / 256, 256, 0, stream>>>(x, xhi, xlo, B * D);

  auto run_mlp = [&](const float* w0, const float* b0, const float* w1,
                     const float* b1, const float* w2, float* part, bool is_tanh) {
    prep_w<0><<<(H * D + 255) / 256, 256, 0, stream>>>(w0, w0hi, w0lo, H, D);
    prep_w<1><<<(H * H + 255) / 256, 256, 0, stream>>>(w1, w1hi, w1lo, H, H);
    prep_w<2><<<(D * H + 255) / 256, 256, 0, stream>>>(w2, w2hi, w2lo, D, H);
    dim3 g12(H / 128, B / 128, 1);
    if (is_tanh) {
      gemm_split<0><<<g12, 256, 0, stream>>>(xhi, xlo, w0hi, w0lo, b0,
                                             h1hi, h1lo, nullptr, B, H, D, D / 32);
      gemm_split<0><<<g12, 256, 0, stream>>>(h1hi, h1lo, w1hi, w1lo, b1,
                                             h2hi, h2lo, nullptr, B, H, H, H / 32);
    } else {
      gemm_split<1><<<g12, 256, 0, stream>>>(xhi, xlo, w0hi, w0lo, b0,
                                             h1hi, h1lo, nullptr, B, H, D, D / 32);
      gemm_split<1><<<g12, 256, 0, stream>>>(h1hi, h1lo, w1hi, w1lo, b1,
                                             h2hi, h2lo, nullptr, B, H, H, H / 32);
    }
    // L3: N=128, split-K=4 -> grid 64x4 = 256 blocks
    dim3 g3(1, B / 128, 4);
    gemm_split<2><<<g3, 256, 0, stream>>>(h2hi, h2lo, w2hi, w2lo, nullptr,
                                          nullptr, nullptr, part, B, D, H,
                                          (H / 4) / 32);
  };

  run_mlp(sw0, sb0, sw1, sb1, sw2, pm, true);   // s-MLP (tanh) -> m partials
  run_mlp(tw0, tb0, tw1, tb1, tw2, pa, false);  // t-MLP (relu) -> a partials

  finalize_kernel<<<B / 4, 256, 0, stream>>>(x, pm, pa, sb2, tb2, out_u, out_s);
}

// Round 7
// 609.867 us; speedup vs baseline: 1.1030x; 1.1030x over previous
//
#include <hip/hip_runtime.h>
#include <hip/hip_bf16.h>

typedef unsigned short u16;
typedef __attribute__((ext_vector_type(8))) short bf16x8;   // 8 bf16 = 4 VGPRs (MFMA A/B frag)
typedef __attribute__((ext_vector_type(4))) float f32x4;    // MFMA C/D frag

constexpr int NB = 8192, ND = 128, NH = 2048;

// ---------- bf16 split helpers ----------
__device__ __forceinline__ u16 f2bf(float x) {
  union { float f; unsigned u; } v; v.f = x;
  unsigned r = v.u + 0x7fffu + ((v.u >> 16) & 1u);   // RNE
  return (u16)(r >> 16);
}
__device__ __forceinline__ float bf2f(u16 h) {
  union { unsigned u; float f; } v; v.u = ((unsigned)h) << 16; return v.f;
}
__device__ __forceinline__ void store_split(u16* hi, u16* lo, long i, float v) {
  u16 h = f2bf(v);
  hi[i] = h;
  lo[i] = f2bf(v - bf2f(h));
}

// ---------- degree-sort permutation (closed form) ----------
// deg(h) = h % 127.  2048 = 16*127 + 16 -> degrees 0..15 occur 17x, 16..126 occur 16x.
// sorted index j <-> original hidden index h.
__device__ __forceinline__ int deg_sorted(int j) {          // degree of sorted slot j
  return (j < 272) ? (j / 17) : ((j - 16) >> 4);
}
__device__ __forceinline__ int perm_h(int j) {              // sorted slot -> original h
  int g, r;
  if (j < 272) { g = j / 17; r = j - g * 17; }
  else         { g = (j - 16) >> 4; r = (j - 16) & 15; }
  return g + 127 * r;
}
__device__ __forceinline__ int offset_of_deg(int g) {       // first sorted slot with degree >= g
  return (g < 16) ? 17 * g : 16 * g + 16;
}

// async global->LDS, 16B per lane (dest must be wave-uniform base + lane*16)
__device__ __forceinline__ void gll16(const u16* g, u16* l) {
  __builtin_amdgcn_global_load_lds(
      (const __attribute__((address_space(1))) unsigned*)g,
      (__attribute__((address_space(3))) unsigned*)l, 16, 0, 0);
}

__device__ __forceinline__ f32x4 mfma_bb(bf16x8 a, bf16x8 b, f32x4 c) {
  return __builtin_amdgcn_mfma_f32_16x16x32_bf16(a, b, c, 0, 0, 0);
}

// ---------- fused prep: split x (PHASE 0 only) + mask/permute/split one MLP's weights ----------
// segment layout (blocks of 256):
//   [x: 4096 (PHASE 0)] [w0: 1024] [w1: 16384] [w2: 1024] [b0: 8] [b1: 8]
template <int PHASE>
__global__ void prep_all(const float* __restrict__ x,
                         const float* __restrict__ w0, const float* __restrict__ b0,
                         const float* __restrict__ w1, const float* __restrict__ b1,
                         const float* __restrict__ w2,
                         u16* __restrict__ xhi, u16* __restrict__ xlo,
                         u16* __restrict__ w0hi, u16* __restrict__ w0lo,
                         u16* __restrict__ w1hi, u16* __restrict__ w1lo,
                         u16* __restrict__ w2hi, u16* __restrict__ w2lo,
                         float* __restrict__ b0p, float* __restrict__ b1p) {
  constexpr int XB  = (NB * ND) / 256;   // 4096
  constexpr int W0B = (NH * ND) / 256;   // 1024
  constexpr int W1B = (NH * NH) / 256;   // 16384
  constexpr int W2B = (ND * NH) / 256;   // 1024
  constexpr int BB  = NH / 256;          // 8
  int bid = blockIdx.x;
  const int tid = threadIdx.x;

  if (PHASE == 0) {
    if (bid < XB) {
      long i = (long)bid * 256 + tid;
      store_split(xhi, xlo, i, x[i]);
      return;
    }
    bid -= XB;
  }
  if (bid < W0B) {                       // w0' [H,D]: row-permuted + m_in mask (deg(row) >= d)
    int i = bid * 256 + tid;
    int r_out = i >> 7, c = i & 127;
    float v = (deg_sorted(r_out) >= c) ? w0[perm_h(r_out) * ND + c] : 0.0f;
    store_split(w0hi, w0lo, i, v);
    return;
  }
  bid -= W0B;
  if (bid < W1B) {                       // w1'' [H,H]: both dims permuted + m_h mask
    long i = (long)bid * 256 + tid;
    int r_out = (int)(i >> 11), c_out = (int)(i & 2047);
    float v = (deg_sorted(r_out) >= deg_sorted(c_out))
                  ? w1[(long)perm_h(r_out) * NH + perm_h(c_out)] : 0.0f;
    store_split(w1hi, w1lo, i, v);
    return;
  }
  bid -= W1B;
  if (bid < W2B) {                       // w2' [D,H]: col-permuted + m_out mask ((d-1) >= deg)
    int i = bid * 256 + tid;
    int r = i >> 11, c_out = i & 2047;
    float v = ((r - 1) >= deg_sorted(c_out)) ? w2[(r << 11) + perm_h(c_out)] : 0.0f;
    store_split(w2hi, w2lo, i, v);
    return;
  }
  bid -= W2B;
  if (bid < BB) { int j = bid * 256 + tid; b0p[j] = b0[perm_h(j)]; return; }
  bid -= BB;
  { int j = bid * 256 + tid; b1p[j] = b1[perm_h(j)]; }
}

// ---------- split-bf16 NT GEMM:  C[M,N] = (Ahi+Alo)[M,K] . (Bhi+Blo)[N,K]^T ----------
// 128x128 tile, 4 waves (2x2, each 64x64 = 4x4 frags of 16x16), BK=32.
// ACT 0: +bias, tanh, store split-bf16 h planes
// ACT 1: +bias, relu, store split-bf16 h planes
// ACT 2: no bias/act, store fp32 partial plane Cf + z*M*N (split-K over blockIdx.z)
// BOUND 0: ksteps arg   BOUND 1 (L1): K-cols masked past deg   BOUND 2 (L2): staircase K-bound
template <int ACT, int BOUND>
__global__ __launch_bounds__(256, 2) void gemm_split(
    const u16* __restrict__ Ahi, const u16* __restrict__ Alo,
    const u16* __restrict__ Bhi, const u16* __restrict__ Blo,
    const float* __restrict__ bias,
    u16* __restrict__ Chi, u16* __restrict__ Clo,
    float* __restrict__ Cf,
    int M, int N, int K, int ksteps_arg) {
  const int tid = threadIdx.x;
  const int l = tid & 63;
  const int w = tid >> 6;
  const int wr = w >> 1, wc = w & 1;
  const int bm = blockIdx.y * 128;
  const int ntile = gridDim.x - 1 - blockIdx.x;   // reversed: heavy (high-deg) tiles first
  const int bn = ntile * 128;
  int ksteps;
  if (BOUND == 1) {
    int ghi = deg_sorted(bn + 127);
    ksteps = (ghi + 1 + 31) >> 5;                 // cols d > ghi are all-masked in B
  } else if (BOUND == 2) {
    int ghi = deg_sorted(bn + 127);
    ksteps = (offset_of_deg(ghi + 1) + 31) >> 5;  // K-slots with deg > ghi are all-masked
  } else {
    ksteps = ksteps_arg;
  }
  const long kbase = (long)blockIdx.z * ksteps * 32;

  __shared__ __align__(16) u16 sAhi[4096];
  __shared__ __align__(16) u16 sAlo[4096];
  __shared__ __align__(16) u16 sBhi[4096];
  __shared__ __align__(16) u16 sBlo[4096];

  f32x4 acc[4][4] = {};

  // staging: thread t copies 8 bf16 (16B): row = t>>2 (+64 for 2nd half), col = (t&3)*8
  const int srow = tid >> 2;
  const int scol = (tid & 3) << 3;
  const long aOff0 = (long)(bm + srow) * K + scol + kbase;
  const long aOff1 = aOff0 + 64L * K;
  const long bOff0 = (long)(bn + srow) * K + scol + kbase;
  const long bOff1 = bOff0 + 64L * K;
  const int ldst0 = tid * 8;
  const int ldst1 = 2048 + tid * 8;

  const int fr = l & 15, fq = l >> 4;

  for (int ks = 0; ks < ksteps; ++ks) {
    const long kk = (long)ks * 32;
    __syncthreads();
    gll16(Ahi + aOff0 + kk, sAhi + ldst0);
    gll16(Ahi + aOff1 + kk, sAhi + ldst1);
    gll16(Alo + aOff0 + kk, sAlo + ldst0);
    gll16(Alo + aOff1 + kk, sAlo + ldst1);
    gll16(Bhi + bOff0 + kk, sBhi + ldst0);
    gll16(Bhi + bOff1 + kk, sBhi + ldst1);
    gll16(Blo + bOff0 + kk, sBlo + ldst0);
    gll16(Blo + bOff1 + kk, sBlo + ldst1);
    __syncthreads();

    bf16x8 ah[4], alo[4], bh[4], blo[4];
#pragma unroll
    for (int m = 0; m < 4; ++m) {
      const int off = (wr * 64 + m * 16 + fr) * 32 + fq * 8;
      ah[m]  = *(const bf16x8*)(sAhi + off);
      alo[m] = *(const bf16x8*)(sAlo + off);
    }
#pragma unroll
    for (int n = 0; n < 4; ++n) {
      const int off = (wc * 64 + n * 16 + fr) * 32 + fq * 8;
      bh[n]  = *(const bf16x8*)(sBhi + off);
      blo[n] = *(const bf16x8*)(sBlo + off);
    }
#pragma unroll
    for (int m = 0; m < 4; ++m)
#pragma unroll
      for (int n = 0; n < 4; ++n) {
        acc[m][n] = mfma_bb(ah[m],  bh[n],  acc[m][n]);
        acc[m][n] = mfma_bb(alo[m], bh[n],  acc[m][n]);
        acc[m][n] = mfma_bb(ah[m],  blo[n], acc[m][n]);
      }
  }

  // epilogue; C/D layout: col = lane&15, row = (lane>>4)*4 + reg
  if (ACT == 2) {
    float* out = Cf + (long)blockIdx.z * M * N;
#pragma unroll
    for (int m = 0; m < 4; ++m) {
      const int row = bm + wr * 64 + m * 16 + fq * 4;
#pragma unroll
      for (int n = 0; n < 4; ++n) {
        const int col = bn + wc * 64 + n * 16 + fr;
#pragma unroll
        for (int r = 0; r < 4; ++r)
          out[(long)(row + r) * N + col] = acc[m][n][r];
      }
    }
  } else {
#pragma unroll
    for (int m = 0; m < 4; ++m) {
      const int row = bm + wr * 64 + m * 16 + fq * 4;
#pragma unroll
      for (int n = 0; n < 4; ++n) {
        const int col = bn + wc * 64 + n * 16 + fr;
        const float bv = bias[col];
#pragma unroll
        for (int r = 0; r < 4; ++r) {
          float z = acc[m][n][r] + bv;
          float h = (ACT == 0) ? tanhf(z) : fmaxf(z, 0.0f);
          long idx = (long)(row + r) * N + col;
          store_split(Chi, Clo, idx, h);
        }
      }
    }
  }
}

// ---------- finalize: m = sum(pm)+s_b2, a = sum(pa)+t_b2, u=(x-m)exp(-a), -sum(a) ----------
__global__ void finalize_kernel(const float* __restrict__ x,
                                const float* __restrict__ pm,
                                const float* __restrict__ pa,
                                const float* __restrict__ sb2,
                                const float* __restrict__ tb2,
                                float* __restrict__ out_u,
                                float* __restrict__ out_s) {
  const int b = blockIdx.x * 4 + (threadIdx.x >> 6);
  const int l = threadIdx.x & 63;
  const long base = (long)b * 128;
  float m0 = sb2[l], m1 = sb2[64 + l];
  float a0 = tb2[l], a1 = tb2[64 + l];
#pragma unroll
  for (int k = 0; k < 4; ++k) {
    const long o = (long)k * ((long)NB * ND) + base;
    m0 += pm[o + l];      m1 += pm[o + 64 + l];
    a0 += pa[o + l];      a1 += pa[o + 64 + l];
  }
  out_u[base + l]      = (x[base + l]      - m0) * expf(-a0);
  out_u[base + 64 + l] = (x[base + 64 + l] - m1) * expf(-a1);
  float s = a0 + a1;
#pragma unroll
  for (int off = 32; off; off >>= 1) s += __shfl_down(s, off);
  if (l == 0) out_s[b] = -s;
}

extern "C" void kernel_launch(void* const* d_in, const int* in_sizes, int n_in,
                              void* d_out, int out_size, void* d_ws, size_t ws_size,
                              hipStream_t stream) {
  (void)in_sizes; (void)n_in; (void)out_size; (void)ws_size;
  const float* x   = (const float*)d_in[0];
  const float* sw0 = (const float*)d_in[1];
  const float* sb0 = (const float*)d_in[2];
  const float* sw1 = (const float*)d_in[3];
  const float* sb1 = (const float*)d_in[4];
  const float* sw2 = (const float*)d_in[5];
  const float* sb2 = (const float*)d_in[6];
  const float* tw0 = (const float*)d_in[7];
  const float* tb0 = (const float*)d_in[8];
  const float* tw1 = (const float*)d_in[9];
  const float* tb1 = (const float*)d_in[10];
  const float* tw2 = (const float*)d_in[11];
  const float* tb2 = (const float*)d_in[12];

  // ---- workspace layout (~190 MB; w-plane buffers reused across the two MLPs) ----
  char* ws = (char*)d_ws;
  size_t off = 0;
  auto alloc = [&](size_t bytes) {
    void* p = ws + off;
    off += (bytes + 255) & ~(size_t)255;
    return p;
  };
  u16* xhi  = (u16*)alloc((size_t)NB * ND * 2);
  u16* xlo  = (u16*)alloc((size_t)NB * ND * 2);
  u16* w0hi = (u16*)alloc((size_t)NH * ND * 2);
  u16* w0lo = (u16*)alloc((size_t)NH * ND * 2);
  u16* w1hi = (u16*)alloc((size_t)NH * NH * 2);
  u16* w1lo = (u16*)alloc((size_t)NH * NH * 2);
  u16* w2hi = (u16*)alloc((size_t)ND * NH * 2);
  u16* w2lo = (u16*)alloc((size_t)ND * NH * 2);
  u16* h1hi = (u16*)alloc((size_t)NB * NH * 2);
  u16* h1lo = (u16*)alloc((size_t)NB * NH * 2);
  u16* h2hi = (u16*)alloc((size_t)NB * NH * 2);
  u16* h2lo = (u16*)alloc((size_t)NB * NH * 2);
  float* pm  = (float*)alloc((size_t)4 * NB * ND * 4);
  float* pa  = (float*)alloc((size_t)4 * NB * ND * 4);
  float* b0p = (float*)alloc((size_t)NH * 4);
  float* b1p = (float*)alloc((size_t)NH * 4);

  float* out_u = (float*)d_out;
  float* out_s = out_u + (long)NB * ND;

  constexpr int XB  = (NB * ND) / 256;
  constexpr int WSEG = (NH * ND) / 256 + (NH * NH) / 256 + (ND * NH) / 256 + 2 * (NH / 256);

  auto run_mlp = [&](int phase, const float* w0, const float* b0, const float* w1,
                     const float* b1, const float* w2, float* part, bool is_tanh) {
    if (phase == 0)
      prep_all<0><<<XB + WSEG, 256, 0, stream>>>(x, w0, b0, w1, b1, w2,
                                                 xhi, xlo, w0hi, w0lo, w1hi, w1lo,
                                                 w2hi, w2lo, b0p, b1p);
    else
      prep_all<1><<<WSEG, 256, 0, stream>>>(x, w0, b0, w1, b1, w2,
                                            xhi, xlo, w0hi, w0lo, w1hi, w1lo,
                                            w2hi, w2lo, b0p, b1p);
    dim3 g12(NH / 128, NB / 128, 1);
    if (is_tanh) {
      gemm_split<0, 1><<<g12, 256, 0, stream>>>(xhi, xlo, w0hi, w0lo, b0p,
                                                h1hi, h1lo, nullptr, NB, NH, ND, 0);
      gemm_split<0, 2><<<g12, 256, 0, stream>>>(h1hi, h1lo, w1hi, w1lo, b1p,
                                                h2hi, h2lo, nullptr, NB, NH, NH, 0);
    } else {
      gemm_split<1, 1><<<g12, 256, 0, stream>>>(xhi, xlo, w0hi, w0lo, b0p,
                                                h1hi, h1lo, nullptr, NB, NH, ND, 0);
      gemm_split<1, 2><<<g12, 256, 0, stream>>>(h1hi, h1lo, w1hi, w1lo, b1p,
                                                h2hi, h2lo, nullptr, NB, NH, NH, 0);
    }
    // L3: N=128, split-K=4 -> grid 64x4 = 256 blocks
    dim3 g3(1, NB / 128, 4);
    gemm_split<2, 0><<<g3, 256, 0, stream>>>(h2hi, h2lo, w2hi, w2lo, nullptr,
                                             nullptr, nullptr, part, NB, ND, NH,
                                             (NH / 4) / 32);
  };

  run_mlp(0, sw0, sb0, sw1, sb1, sw2, pm, true);   // s-MLP (tanh) -> m partials
  run_mlp(1, tw0, tb0, tw1, tb1, tw2, pa, false);  // t-MLP (relu) -> a partials

  finalize_kernel<<<NB / 4, 256, 0, stream>>>(x, pm, pa, sb2, tb2, out_u, out_s);
}

// Round 8
// 601.657 us; speedup vs baseline: 1.1180x; 1.0136x over previous
//
#include <hip/hip_runtime.h>
#include <hip/hip_bf16.h>

typedef unsigned short u16;
typedef __attribute__((ext_vector_type(8))) short bf16x8;   // 8 bf16 = 4 VGPRs (MFMA A/B frag)
typedef __attribute__((ext_vector_type(4))) float f32x4;    // MFMA C/D frag

constexpr int NB = 8192, ND = 128, NH = 2048;

// ---------- bf16 split helpers ----------
__device__ __forceinline__ u16 f2bf(float x) {
  union { float f; unsigned u; } v; v.f = x;
  unsigned r = v.u + 0x7fffu + ((v.u >> 16) & 1u);   // RNE
  return (u16)(r >> 16);
}
__device__ __forceinline__ float bf2f(u16 h) {
  union { unsigned u; float f; } v; v.u = ((unsigned)h) << 16; return v.f;
}
__device__ __forceinline__ void store_split(u16* hi, u16* lo, long i, float v) {
  u16 h = f2bf(v);
  hi[i] = h;
  lo[i] = f2bf(v - bf2f(h));
}

// ---------- degree-sort permutation (closed form) ----------
// deg(h) = h % 127.  2048 = 16*127 + 16 -> degrees 0..15 occur 17x, 16..126 occur 16x.
__device__ __forceinline__ int deg_sorted(int j) {          // degree of sorted slot j
  return (j < 272) ? (j / 17) : ((j - 16) >> 4);
}
__device__ __forceinline__ int perm_h(int j) {              // sorted slot -> original h
  int g, r;
  if (j < 272) { g = j / 17; r = j - g * 17; }
  else         { g = (j - 16) >> 4; r = (j - 16) & 15; }
  return g + 127 * r;
}
__device__ __forceinline__ int offset_of_deg(int g) {       // first sorted slot with degree >= g
  return (g < 16) ? 17 * g : 16 * g + 16;
}

// async global->LDS, 16B per lane (dest must be wave-uniform base + lane*16)
__device__ __forceinline__ void gll16(const u16* g, u16* l) {
  __builtin_amdgcn_global_load_lds(
      (const __attribute__((address_space(1))) unsigned*)g,
      (__attribute__((address_space(3))) unsigned*)l, 16, 0, 0);
}

__device__ __forceinline__ f32x4 mfma_bb(bf16x8 a, bf16x8 b, f32x4 c) {
  return __builtin_amdgcn_mfma_f32_16x16x32_bf16(a, b, c, 0, 0, 0);
}

// ---------- prep (small): split x (PHASE 0 only) + w0 row-gather + biases ----------
// segments (blocks of 256): [x: 4096 (PHASE 0)] [w0: 1024] [b0: 8] [b1: 8]
template <int PHASE>
__global__ void prep_small(const float* __restrict__ x,
                           const float* __restrict__ w0,
                           const float* __restrict__ b0, const float* __restrict__ b1,
                           u16* __restrict__ xhi, u16* __restrict__ xlo,
                           u16* __restrict__ w0hi, u16* __restrict__ w0lo,
                           float* __restrict__ b0p, float* __restrict__ b1p) {
  constexpr int XB  = (NB * ND) / 256;   // 4096
  constexpr int W0B = (NH * ND) / 256;   // 1024
  int bid = blockIdx.x;
  const int tid = threadIdx.x;

  if (PHASE == 0) {
    if (bid < XB) {
      long i = (long)bid * 256 + tid;
      store_split(xhi, xlo, i, x[i]);
      return;
    }
    bid -= XB;
  }
  if (bid < W0B) {                       // w0' [H,D]: row-permuted + m_in mask (deg(row) >= d)
    int i = bid * 256 + tid;             // row reads are contiguous (coalesced)
    int r_out = i >> 7, c = i & 127;
    float v = (deg_sorted(r_out) >= c) ? w0[perm_h(r_out) * ND + c] : 0.0f;
    store_split(w0hi, w0lo, i, v);
    return;
  }
  bid -= W0B;
  if (bid < 8) { int j = bid * 256 + tid; b0p[j] = b0[perm_h(j)]; return; }
  { int j = (bid - 8) * 256 + tid; b1p[j] = b1[perm_h(j)]; }
}

// ---------- prep (rows): w1 (both-dim permute) and w2 (col permute) via LDS row-stage ----
// One block per OUTPUT row. Coalesced row read -> LDS; permuted gather from LDS;
// coalesced masked split-store. Kills the scattered 4B global gathers.
__global__ void prep_rows(const float* __restrict__ w1, const float* __restrict__ w2,
                          u16* __restrict__ w1hi, u16* __restrict__ w1lo,
                          u16* __restrict__ w2hi, u16* __restrict__ w2lo) {
  __shared__ float row[NH];
  const int j = blockIdx.x;
  const int tid = threadIdx.x;
  const float* src = (j < NH) ? (w1 + (long)perm_h(j) * NH)
                              : (w2 + (long)(j - NH) * NH);
  const float4* s4 = (const float4*)src;
  float4* r4 = (float4*)row;
#pragma unroll
  for (int i = 0; i < 2; ++i) r4[tid + i * 256] = s4[tid + i * 256];
  __syncthreads();
  if (j < NH) {
    const int dj = deg_sorted(j);
    const long base = (long)j * NH;
#pragma unroll
    for (int k = 0; k < 8; ++k) {
      int c = k * 256 + tid;
      float v = (dj >= deg_sorted(c)) ? row[perm_h(c)] : 0.0f;
      store_split(w1hi, w1lo, base + c, v);
    }
  } else {
    const int r = j - NH;
    const long base = (long)r * NH;
#pragma unroll
    for (int k = 0; k < 8; ++k) {
      int c = k * 256 + tid;
      float v = ((r - 1) >= deg_sorted(c)) ? row[perm_h(c)] : 0.0f;
      store_split(w2hi, w2lo, base + c, v);
    }
  }
}

// ---------- split-bf16 NT GEMM:  C[M,N] = (Ahi+Alo)[M,K] . (Bhi+Blo)[N,K]^T ----------
// 128x128 tile, 4 waves (2x2, each 64x64 = 4x4 frags of 16x16), BK=32.
// ACT 0: +bias, tanh  ACT 1: +bias, relu  ACT 2: fp32 partials (split-K over blockIdx.z)
// BOUND 0: ksteps arg  BOUND 1 (L1): deg-bound  BOUND 2 (L2): staircase K-bound
// N-tile order: pair-interleaved heavy/light so the resident mix stays balanced
// (heavy-first left an all-light, near-zero-MFMA tail -> 22% MfmaUtil in r7).
template <int ACT, int BOUND>
__global__ __launch_bounds__(256, 3) void gemm_split(
    const u16* __restrict__ Ahi, const u16* __restrict__ Alo,
    const u16* __restrict__ Bhi, const u16* __restrict__ Blo,
    const float* __restrict__ bias,
    u16* __restrict__ Chi, u16* __restrict__ Clo,
    float* __restrict__ Cf,
    int M, int N, int K, int ksteps_arg) {
  const int tid = threadIdx.x;
  const int l = tid & 63;
  const int w = tid >> 6;
  const int wr = w >> 1, wc = w & 1;
  const int bm = blockIdx.y * 128;
  const int NT = gridDim.x;
  const int bx = blockIdx.x;
  const int ntile = (bx & 1) ? (bx >> 1) : (NT - 1 - (bx >> 1));  // heavy,light,heavy,...
  const int bn = ntile * 128;
  int ksteps;
  if (BOUND == 1) {
    int ghi = deg_sorted(bn + 127);
    ksteps = (ghi + 1 + 31) >> 5;                 // cols d > ghi are all-masked in B
  } else if (BOUND == 2) {
    int ghi = deg_sorted(bn + 127);
    ksteps = (offset_of_deg(ghi + 1) + 31) >> 5;  // K-slots with deg > ghi are all-masked
  } else {
    ksteps = ksteps_arg;
  }
  const long kbase = (long)blockIdx.z * ksteps * 32;

  __shared__ __align__(16) u16 sAhi[4096];
  __shared__ __align__(16) u16 sAlo[4096];
  __shared__ __align__(16) u16 sBhi[4096];
  __shared__ __align__(16) u16 sBlo[4096];

  f32x4 acc[4][4] = {};

  // staging: thread t copies 8 bf16 (16B): row = t>>2 (+64 for 2nd half), col = (t&3)*8
  const int srow = tid >> 2;
  const int scol = (tid & 3) << 3;
  const long aOff0 = (long)(bm + srow) * K + scol + kbase;
  const long aOff1 = aOff0 + 64L * K;
  const long bOff0 = (long)(bn + srow) * K + scol + kbase;
  const long bOff1 = bOff0 + 64L * K;
  const int ldst0 = tid * 8;
  const int ldst1 = 2048 + tid * 8;

  const int fr = l & 15, fq = l >> 4;

  for (int ks = 0; ks < ksteps; ++ks) {
    const long kk = (long)ks * 32;
    __syncthreads();
    gll16(Ahi + aOff0 + kk, sAhi + ldst0);
    gll16(Ahi + aOff1 + kk, sAhi + ldst1);
    gll16(Alo + aOff0 + kk, sAlo + ldst0);
    gll16(Alo + aOff1 + kk, sAlo + ldst1);
    gll16(Bhi + bOff0 + kk, sBhi + ldst0);
    gll16(Bhi + bOff1 + kk, sBhi + ldst1);
    gll16(Blo + bOff0 + kk, sBlo + ldst0);
    gll16(Blo + bOff1 + kk, sBlo + ldst1);
    __syncthreads();

    bf16x8 ah[4], alo[4], bh[4], blo[4];
#pragma unroll
    for (int m = 0; m < 4; ++m) {
      const int off = (wr * 64 + m * 16 + fr) * 32 + fq * 8;
      ah[m]  = *(const bf16x8*)(sAhi + off);
      alo[m] = *(const bf16x8*)(sAlo + off);
    }
#pragma unroll
    for (int n = 0; n < 4; ++n) {
      const int off = (wc * 64 + n * 16 + fr) * 32 + fq * 8;
      bh[n]  = *(const bf16x8*)(sBhi + off);
      blo[n] = *(const bf16x8*)(sBlo + off);
    }
#pragma unroll
    for (int m = 0; m < 4; ++m)
#pragma unroll
      for (int n = 0; n < 4; ++n) {
        acc[m][n] = mfma_bb(ah[m],  bh[n],  acc[m][n]);
        acc[m][n] = mfma_bb(alo[m], bh[n],  acc[m][n]);
        acc[m][n] = mfma_bb(ah[m],  blo[n], acc[m][n]);
      }
  }

  // epilogue; C/D layout: col = lane&15, row = (lane>>4)*4 + reg
  if (ACT == 2) {
    float* out = Cf + (long)blockIdx.z * M * N;
#pragma unroll
    for (int m = 0; m < 4; ++m) {
      const int row = bm + wr * 64 + m * 16 + fq * 4;
#pragma unroll
      for (int n = 0; n < 4; ++n) {
        const int col = bn + wc * 64 + n * 16 + fr;
#pragma unroll
        for (int r = 0; r < 4; ++r)
          out[(long)(row + r) * N + col] = acc[m][n][r];
      }
    }
  } else {
#pragma unroll
    for (int m = 0; m < 4; ++m) {
      const int row = bm + wr * 64 + m * 16 + fq * 4;
#pragma unroll
      for (int n = 0; n < 4; ++n) {
        const int col = bn + wc * 64 + n * 16 + fr;
        const float bv = bias[col];
#pragma unroll
        for (int r = 0; r < 4; ++r) {
          float z = acc[m][n][r] + bv;
          float h = (ACT == 0) ? tanhf(z) : fmaxf(z, 0.0f);
          long idx = (long)(row + r) * N + col;
          store_split(Chi, Clo, idx, h);
        }
      }
    }
  }
}

// ---------- finalize: m = sum(pm)+s_b2, a = sum(pa)+t_b2, u=(x-m)exp(-a), -sum(a) ----------
__global__ void finalize_kernel(const float* __restrict__ x,
                                const float* __restrict__ pm,
                                const float* __restrict__ pa,
                                const float* __restrict__ sb2,
                                const float* __restrict__ tb2,
                                float* __restrict__ out_u,
                                float* __restrict__ out_s) {
  const int b = blockIdx.x * 4 + (threadIdx.x >> 6);
  const int l = threadIdx.x & 63;
  const long base = (long)b * 128;
  float m0 = sb2[l], m1 = sb2[64 + l];
  float a0 = tb2[l], a1 = tb2[64 + l];
#pragma unroll
  for (int k = 0; k < 4; ++k) {
    const long o = (long)k * ((long)NB * ND) + base;
    m0 += pm[o + l];      m1 += pm[o + 64 + l];
    a0 += pa[o + l];      a1 += pa[o + 64 + l];
  }
  out_u[base + l]      = (x[base + l]      - m0) * expf(-a0);
  out_u[base + 64 + l] = (x[base + 64 + l] - m1) * expf(-a1);
  float s = a0 + a1;
#pragma unroll
  for (int off = 32; off; off >>= 1) s += __shfl_down(s, off);
  if (l == 0) out_s[b] = -s;
}

extern "C" void kernel_launch(void* const* d_in, const int* in_sizes, int n_in,
                              void* d_out, int out_size, void* d_ws, size_t ws_size,
                              hipStream_t stream) {
  (void)in_sizes; (void)n_in; (void)out_size; (void)ws_size;
  const float* x   = (const float*)d_in[0];
  const float* sw0 = (const float*)d_in[1];
  const float* sb0 = (const float*)d_in[2];
  const float* sw1 = (const float*)d_in[3];
  const float* sb1 = (const float*)d_in[4];
  const float* sw2 = (const float*)d_in[5];
  const float* sb2 = (const float*)d_in[6];
  const float* tw0 = (const float*)d_in[7];
  const float* tb0 = (const float*)d_in[8];
  const float* tw1 = (const float*)d_in[9];
  const float* tb1 = (const float*)d_in[10];
  const float* tw2 = (const float*)d_in[11];
  const float* tb2 = (const float*)d_in[12];

  // ---- workspace layout (~190 MB; w-plane buffers reused across the two MLPs) ----
  char* ws = (char*)d_ws;
  size_t off = 0;
  auto alloc = [&](size_t bytes) {
    void* p = ws + off;
    off += (bytes + 255) & ~(size_t)255;
    return p;
  };
  u16* xhi  = (u16*)alloc((size_t)NB * ND * 2);
  u16* xlo  = (u16*)alloc((size_t)NB * ND * 2);
  u16* w0hi = (u16*)alloc((size_t)NH * ND * 2);
  u16* w0lo = (u16*)alloc((size_t)NH * ND * 2);
  u16* w1hi = (u16*)alloc((size_t)NH * NH * 2);
  u16* w1lo = (u16*)alloc((size_t)NH * NH * 2);
  u16* w2hi = (u16*)alloc((size_t)ND * NH * 2);
  u16* w2lo = (u16*)alloc((size_t)ND * NH * 2);
  u16* h1hi = (u16*)alloc((size_t)NB * NH * 2);
  u16* h1lo = (u16*)alloc((size_t)NB * NH * 2);
  u16* h2hi = (u16*)alloc((size_t)NB * NH * 2);
  u16* h2lo = (u16*)alloc((size_t)NB * NH * 2);
  float* pm  = (float*)alloc((size_t)4 * NB * ND * 4);
  float* pa  = (float*)alloc((size_t)4 * NB * ND * 4);
  float* b0p = (float*)alloc((size_t)NH * 4);
  float* b1p = (float*)alloc((size_t)NH * 4);

  float* out_u = (float*)d_out;
  float* out_s = out_u + (long)NB * ND;

  constexpr int XB   = (NB * ND) / 256;                    // 4096
  constexpr int WSEG = (NH * ND) / 256 + 2 * (NH / 256);   // w0 + b0 + b1 = 1040

  auto run_mlp = [&](int phase, const float* w0, const float* b0, const float* w1,
                     const float* b1, const float* w2, float* part, bool is_tanh) {
    if (phase == 0)
      prep_small<0><<<XB + WSEG, 256, 0, stream>>>(x, w0, b0, b1, xhi, xlo,
                                                   w0hi, w0lo, b0p, b1p);
    else
      prep_small<1><<<WSEG, 256, 0, stream>>>(x, w0, b0, b1, xhi, xlo,
                                              w0hi, w0lo, b0p, b1p);
    prep_rows<<<NH + ND, 256, 0, stream>>>(w1, w2, w1hi, w1lo, w2hi, w2lo);
    dim3 g12(NH / 128, NB / 128, 1);
    if (is_tanh) {
      gemm_split<0, 1><<<g12, 256, 0, stream>>>(xhi, xlo, w0hi, w0lo, b0p,
                                                h1hi, h1lo, nullptr, NB, NH, ND, 0);
      gemm_split<0, 2><<<g12, 256, 0, stream>>>(h1hi, h1lo, w1hi, w1lo, b1p,
                                                h2hi, h2lo, nullptr, NB, NH, NH, 0);
    } else {
      gemm_split<1, 1><<<g12, 256, 0, stream>>>(xhi, xlo, w0hi, w0lo, b0p,
                                                h1hi, h1lo, nullptr, NB, NH, ND, 0);
      gemm_split<1, 2><<<g12, 256, 0, stream>>>(h1hi, h1lo, w1hi, w1lo, b1p,
                                                h2hi, h2lo, nullptr, NB, NH, NH, 0);
    }
    // L3: N=128, split-K=4 -> grid 64x4 = 256 blocks
    dim3 g3(1, NB / 128, 4);
    gemm_split<2, 0><<<g3, 256, 0, stream>>>(h2hi, h2lo, w2hi, w2lo, nullptr,
                                             nullptr, nullptr, part, NB, ND, NH,
                                             (NH / 4) / 32);
  };

  run_mlp(0, sw0, sb0, sw1, sb1, sw2, pm, true);   // s-MLP (tanh) -> m partials
  run_mlp(1, tw0, tb0, tw1, tb1, tw2, pa, false);  // t-MLP (relu) -> a partials

  finalize_kernel<<<NB / 4, 256, 0, stream>>>(x, pm, pa, sb2, tb2, out_u, out_s);
}

// Round 13
// 591.049 us; speedup vs baseline: 1.1381x; 1.0179x over previous
//
#include <hip/hip_runtime.h>
#include <hip/hip_bf16.h>

typedef unsigned short u16;
typedef __attribute__((ext_vector_type(8))) short bf16x8;   // 8 bf16 = 4 VGPRs (MFMA A/B frag)
typedef __attribute__((ext_vector_type(4))) float f32x4;    // MFMA C/D frag

constexpr int NB = 8192, ND = 128, NH = 2048;

// ---------- bf16 split helpers ----------
__device__ __forceinline__ u16 f2bf(float x) {
  union { float f; unsigned u; } v; v.f = x;
  unsigned r = v.u + 0x7fffu + ((v.u >> 16) & 1u);   // RNE
  return (u16)(r >> 16);
}
__device__ __forceinline__ float bf2f(u16 h) {
  union { unsigned u; float f; } v; v.u = ((unsigned)h) << 16; return v.f;
}
__device__ __forceinline__ void store_split(u16* hi, u16* lo, long i, float v) {
  u16 h = f2bf(v);
  hi[i] = h;
  lo[i] = f2bf(v - bf2f(h));
}

// ---------- degree-sort permutation (closed form) ----------
// deg(h) = h % 127.  2048 = 16*127 + 16 -> degrees 0..15 occur 17x, 16..126 occur 16x.
__device__ __forceinline__ int deg_sorted(int j) {          // degree of sorted slot j
  return (j < 272) ? (j / 17) : ((j - 16) >> 4);
}
__device__ __forceinline__ int perm_h(int j) {              // sorted slot -> original h
  int g, r;
  if (j < 272) { g = j / 17; r = j - g * 17; }
  else         { g = (j - 16) >> 4; r = (j - 16) & 15; }
  return g + 127 * r;
}
__device__ __forceinline__ int offset_of_deg(int g) {       // first sorted slot with degree >= g
  return (g < 16) ? 17 * g : 16 * g + 16;
}

// async global->LDS, 16B per lane (dest must be wave-uniform base + lane*16)
__device__ __forceinline__ void gll16(const u16* g, u16* l) {
  __builtin_amdgcn_global_load_lds(
      (const __attribute__((address_space(1))) unsigned*)g,
      (__attribute__((address_space(3))) unsigned*)l, 16, 0, 0);
}

__device__ __forceinline__ f32x4 mfma_bb(bf16x8 a, bf16x8 b, f32x4 c) {
  return __builtin_amdgcn_mfma_f32_16x16x32_bf16(a, b, c, 0, 0, 0);
}

// ---------- init: zero ALL 64 work-queue counter slots (ws re-poisoned 0xAA each call).
// r9 crash: only 8 slots were zeroed but slot 64 (out of alloc!) was used -> poisoned
// counter -> negative item -> OOB global_load_lds -> abort. Counters now at slots 0 and 8.
__global__ void init_ctrs(unsigned* __restrict__ c) {
  c[threadIdx.x] = 0u;   // 64 threads cover the whole 256-byte block
}

// ---------- prep (small): split x (PHASE 0 only) + w0 row-gather + biases ----------
// segments (blocks of 256): [x: 4096 (PHASE 0)] [w0: 1024] [b0: 8] [b1: 8]
template <int PHASE>
__global__ void prep_small(const float* __restrict__ x,
                           const float* __restrict__ w0,
                           const float* __restrict__ b0, const float* __restrict__ b1,
                           u16* __restrict__ xhi, u16* __restrict__ xlo,
                           u16* __restrict__ w0hi, u16* __restrict__ w0lo,
                           float* __restrict__ b0p, float* __restrict__ b1p) {
  constexpr int XB  = (NB * ND) / 256;   // 4096
  constexpr int W0B = (NH * ND) / 256;   // 1024
  int bid = blockIdx.x;
  const int tid = threadIdx.x;

  if (PHASE == 0) {
    if (bid < XB) {
      long i = (long)bid * 256 + tid;
      store_split(xhi, xlo, i, x[i]);
      return;
    }
    bid -= XB;
  }
  if (bid < W0B) {                       // w0' [H,D]: row-permuted + m_in mask (deg(row) >= d)
    int i = bid * 256 + tid;             // row reads are contiguous (coalesced)
    int r_out = i >> 7, c = i & 127;
    float v = (deg_sorted(r_out) >= c) ? w0[perm_h(r_out) * ND + c] : 0.0f;
    store_split(w0hi, w0lo, i, v);
    return;
  }
  bid -= W0B;
  if (bid < 8) { int j = bid * 256 + tid; b0p[j] = b0[perm_h(j)]; return; }
  { int j = (bid - 8) * 256 + tid; b1p[j] = b1[perm_h(j)]; }
}

// ---------- prep (rows): w1 (both-dim permute) and w2 (col permute) via LDS row-stage ----
__global__ void prep_rows(const float* __restrict__ w1, const float* __restrict__ w2,
                          u16* __restrict__ w1hi, u16* __restrict__ w1lo,
                          u16* __restrict__ w2hi, u16* __restrict__ w2lo) {
  __shared__ float row[NH];
  const int j = blockIdx.x;
  const int tid = threadIdx.x;
  const float* src = (j < NH) ? (w1 + (long)perm_h(j) * NH)
                              : (w2 + (long)(j - NH) * NH);
  const float4* s4 = (const float4*)src;
  float4* r4 = (float4*)row;
#pragma unroll
  for (int i = 0; i < 2; ++i) r4[tid + i * 256] = s4[tid + i * 256];
  __syncthreads();
  if (j < NH) {
    const int dj = deg_sorted(j);
    const long base = (long)j * NH;
#pragma unroll
    for (int k = 0; k < 8; ++k) {
      int c = k * 256 + tid;
      float v = (dj >= deg_sorted(c)) ? row[perm_h(c)] : 0.0f;
      store_split(w1hi, w1lo, base + c, v);
    }
  } else {
    const int r = j - NH;
    const long base = (long)r * NH;
#pragma unroll
    for (int k = 0; k < 8; ++k) {
      int c = k * 256 + tid;
      float v = ((r - 1) >= deg_sorted(c)) ? row[perm_h(c)] : 0.0f;
      store_split(w2hi, w2lo, base + c, v);
    }
  }
}

// ---------- persistent L2 GEMM: C[NB,NH] = A[NB,NH] . B[NH,NH]^T, staircase K ----------
// Dynamic work queue (atomic counter): static blockIdx->CU mapping cannot be balanced
// (dispatcher round-robins stride 256, even -> parity tricks anti-balance, r8 lesson).
// Items heavy-first; greedy LPT self-balance; tail bounded by one heavy item.
template <int ACT>   // 0: tanh epilogue, 1: relu epilogue
__global__ __launch_bounds__(256, 4) void gemm_l2_persist(
    const u16* __restrict__ Ahi, const u16* __restrict__ Alo,
    const u16* __restrict__ Bhi, const u16* __restrict__ Blo,
    const float* __restrict__ bias,
    u16* __restrict__ Chi, u16* __restrict__ Clo,
    unsigned* __restrict__ ctr) {
  constexpr int K = NH;
  constexpr unsigned NITEMS = (NH / 128) * (NB / 128);   // 16*64 = 1024
  const int tid = threadIdx.x;
  const int l = tid & 63, w = tid >> 6;
  const int wr = w >> 1, wc = w & 1;
  const int fr = l & 15, fq = l >> 4;

  __shared__ __align__(16) u16 sAhi[4096];
  __shared__ __align__(16) u16 sAlo[4096];
  __shared__ __align__(16) u16 sBhi[4096];
  __shared__ __align__(16) u16 sBlo[4096];
  __shared__ unsigned s_item;

  const int srow = tid >> 2;
  const int scol = (tid & 3) << 3;
  const int ldst0 = tid * 8;
  const int ldst1 = 2048 + tid * 8;

  for (;;) {
    if (tid == 0) s_item = atomicAdd(ctr, 1u);
    __syncthreads();
    const unsigned item = s_item;
    if (item >= NITEMS) break;          // unsigned compare: garbage exits, never faults
    const int ntile = 15 - (int)(item >> 6);       // heavy-first (ntile 15 = deepest K)
    const int bm = (int)(item & 63) * 128;
    const int bn = ntile * 128;
    const int ghi = deg_sorted(bn + 127);
    const int ksteps = (offset_of_deg(ghi + 1) + 31) >> 5;

    const long aOff0 = (long)(bm + srow) * K + scol;
    const long aOff1 = aOff0 + 64L * K;
    const long bOff0 = (long)(bn + srow) * K + scol;
    const long bOff1 = bOff0 + 64L * K;

    f32x4 acc[4][4] = {};

    for (int ks = 0; ks < ksteps; ++ks) {
      const long kk = (long)ks * 32;
      __syncthreads();
      gll16(Ahi + aOff0 + kk, sAhi + ldst0);
      gll16(Ahi + aOff1 + kk, sAhi + ldst1);
      gll16(Alo + aOff0 + kk, sAlo + ldst0);
      gll16(Alo + aOff1 + kk, sAlo + ldst1);
      gll16(Bhi + bOff0 + kk, sBhi + ldst0);
      gll16(Bhi + bOff1 + kk, sBhi + ldst1);
      gll16(Blo + bOff0 + kk, sBlo + ldst0);
      gll16(Blo + bOff1 + kk, sBlo + ldst1);
      __syncthreads();

      bf16x8 ah[4], alo[4], bh[4], blo[4];
#pragma unroll
      for (int m = 0; m < 4; ++m) {
        const int off = (wr * 64 + m * 16 + fr) * 32 + fq * 8;
        ah[m]  = *(const bf16x8*)(sAhi + off);
        alo[m] = *(const bf16x8*)(sAlo + off);
      }
#pragma unroll
      for (int n = 0; n < 4; ++n) {
        const int off = (wc * 64 + n * 16 + fr) * 32 + fq * 8;
        bh[n]  = *(const bf16x8*)(sBhi + off);
        blo[n] = *(const bf16x8*)(sBlo + off);
      }
#pragma unroll
      for (int m = 0; m < 4; ++m)
#pragma unroll
        for (int n = 0; n < 4; ++n) {
          acc[m][n] = mfma_bb(ah[m],  bh[n],  acc[m][n]);
          acc[m][n] = mfma_bb(alo[m], bh[n],  acc[m][n]);
          acc[m][n] = mfma_bb(ah[m],  blo[n], acc[m][n]);
        }
    }

    // epilogue; C/D layout: col = lane&15, row = (lane>>4)*4 + reg
#pragma unroll
    for (int m = 0; m < 4; ++m) {
      const int row = bm + wr * 64 + m * 16 + fq * 4;
#pragma unroll
      for (int n = 0; n < 4; ++n) {
        const int col = bn + wc * 64 + n * 16 + fr;
        const float bv = bias[col];
#pragma unroll
        for (int r = 0; r < 4; ++r) {
          float z = acc[m][n][r] + bv;
          float h = (ACT == 0) ? tanhf(z) : fmaxf(z, 0.0f);
          long idx = (long)(row + r) * NH + col;
          store_split(Chi, Clo, idx, h);
        }
      }
    }
  }
}

// ---------- static GEMM (L1: deg-bound K, L3: fp32 split-K partials) ----------
// BOUND 1 (L1): K-cols masked past deg   BOUND 0 (L3): ksteps arg
template <int ACT, int BOUND>   // ACT 0 tanh / 1 relu / 2 fp32-partials
__global__ __launch_bounds__(256, 3) void gemm_split(
    const u16* __restrict__ Ahi, const u16* __restrict__ Alo,
    const u16* __restrict__ Bhi, const u16* __restrict__ Blo,
    const float* __restrict__ bias,
    u16* __restrict__ Chi, u16* __restrict__ Clo,
    float* __restrict__ Cf,
    int M, int N, int K, int ksteps_arg) {
  const int tid = threadIdx.x;
  const int l = tid & 63;
  const int w = tid >> 6;
  const int wr = w >> 1, wc = w & 1;
  const int bm = blockIdx.y * 128;
  const int ntile = gridDim.x - 1 - blockIdx.x;   // heavy-first
  const int bn = ntile * 128;
  int ksteps;
  if (BOUND == 1) {
    int ghi = deg_sorted(bn + 127);
    ksteps = (ghi + 1 + 31) >> 5;                 // cols d > ghi are all-masked in B
  } else {
    ksteps = ksteps_arg;
  }
  const long kbase = (long)blockIdx.z * ksteps * 32;

  __shared__ __align__(16) u16 sAhi[4096];
  __shared__ __align__(16) u16 sAlo[4096];
  __shared__ __align__(16) u16 sBhi[4096];
  __shared__ __align__(16) u16 sBlo[4096];

  f32x4 acc[4][4] = {};

  const int srow = tid >> 2;
  const int scol = (tid & 3) << 3;
  const long aOff0 = (long)(bm + srow) * K + scol + kbase;
  const long aOff1 = aOff0 + 64L * K;
  const long bOff0 = (long)(bn + srow) * K + scol + kbase;
  const long bOff1 = bOff0 + 64L * K;
  const int ldst0 = tid * 8;
  const int ldst1 = 2048 + tid * 8;

  const int fr = l & 15, fq = l >> 4;

  for (int ks = 0; ks < ksteps; ++ks) {
    const long kk = (long)ks * 32;
    __syncthreads();
    gll16(Ahi + aOff0 + kk, sAhi + ldst0);
    gll16(Ahi + aOff1 + kk, sAhi + ldst1);
    gll16(Alo + aOff0 + kk, sAlo + ldst0);
    gll16(Alo + aOff1 + kk, sAlo + ldst1);
    gll16(Bhi + bOff0 + kk, sBhi + ldst0);
    gll16(Bhi + bOff1 + kk, sBhi + ldst1);
    gll16(Blo + bOff0 + kk, sBlo + ldst0);
    gll16(Blo + bOff1 + kk, sBlo + ldst1);
    __syncthreads();

    bf16x8 ah[4], alo[4], bh[4], blo[4];
#pragma unroll
    for (int m = 0; m < 4; ++m) {
      const int off = (wr * 64 + m * 16 + fr) * 32 + fq * 8;
      ah[m]  = *(const bf16x8*)(sAhi + off);
      alo[m] = *(const bf16x8*)(sAlo + off);
    }
#pragma unroll
    for (int n = 0; n < 4; ++n) {
      const int off = (wc * 64 + n * 16 + fr) * 32 + fq * 8;
      bh[n]  = *(const bf16x8*)(sBhi + off);
      blo[n] = *(const bf16x8*)(sBlo + off);
    }
#pragma unroll
    for (int m = 0; m < 4; ++m)
#pragma unroll
      for (int n = 0; n < 4; ++n) {
        acc[m][n] = mfma_bb(ah[m],  bh[n],  acc[m][n]);
        acc[m][n] = mfma_bb(alo[m], bh[n],  acc[m][n]);
        acc[m][n] = mfma_bb(ah[m],  blo[n], acc[m][n]);
      }
  }

  // epilogue; C/D layout: col = lane&15, row = (lane>>4)*4 + reg
  if (ACT == 2) {
    float* out = Cf + (long)blockIdx.z * M * N;
#pragma unroll
    for (int m = 0; m < 4; ++m) {
      const int row = bm + wr * 64 + m * 16 + fq * 4;
#pragma unroll
      for (int n = 0; n < 4; ++n) {
        const int col = bn + wc * 64 + n * 16 + fr;
#pragma unroll
        for (int r = 0; r < 4; ++r)
          out[(long)(row + r) * N + col] = acc[m][n][r];
      }
    }
  } else {
#pragma unroll
    for (int m = 0; m < 4; ++m) {
      const int row = bm + wr * 64 + m * 16 + fq * 4;
#pragma unroll
      for (int n = 0; n < 4; ++n) {
        const int col = bn + wc * 64 + n * 16 + fr;
        const float bv = bias[col];
#pragma unroll
        for (int r = 0; r < 4; ++r) {
          float z = acc[m][n][r] + bv;
          float h = (ACT == 0) ? tanhf(z) : fmaxf(z, 0.0f);
          long idx = (long)(row + r) * N + col;
          store_split(Chi, Clo, idx, h);
        }
      }
    }
  }
}

// ---------- finalize: m = sum(pm)+s_b2, a = sum(pa)+t_b2, u=(x-m)exp(-a), -sum(a) ----------
__global__ void finalize_kernel(const float* __restrict__ x,
                                const float* __restrict__ pm,
                                const float* __restrict__ pa,
                                const float* __restrict__ sb2,
                                const float* __restrict__ tb2,
                                float* __restrict__ out_u,
                                float* __restrict__ out_s) {
  const int b = blockIdx.x * 4 + (threadIdx.x >> 6);
  const int l = threadIdx.x & 63;
  const long base = (long)b * 128;
  float m0 = sb2[l], m1 = sb2[64 + l];
  float a0 = tb2[l], a1 = tb2[64 + l];
#pragma unroll
  for (int k = 0; k < 4; ++k) {
    const long o = (long)k * ((long)NB * ND) + base;
    m0 += pm[o + l];      m1 += pm[o + 64 + l];
    a0 += pa[o + l];      a1 += pa[o + 64 + l];
  }
  out_u[base + l]      = (x[base + l]      - m0) * expf(-a0);
  out_u[base + 64 + l] = (x[base + 64 + l] - m1) * expf(-a1);
  float s = a0 + a1;
#pragma unroll
  for (int off = 32; off; off >>= 1) s += __shfl_down(s, off);
  if (l == 0) out_s[b] = -s;
}

extern "C" void kernel_launch(void* const* d_in, const int* in_sizes, int n_in,
                              void* d_out, int out_size, void* d_ws, size_t ws_size,
                              hipStream_t stream) {
  (void)in_sizes; (void)n_in; (void)out_size; (void)ws_size;
  const float* x   = (const float*)d_in[0];
  const float* sw0 = (const float*)d_in[1];
  const float* sb0 = (const float*)d_in[2];
  const float* sw1 = (const float*)d_in[3];
  const float* sb1 = (const float*)d_in[4];
  const float* sw2 = (const float*)d_in[5];
  const float* sb2 = (const float*)d_in[6];
  const float* tw0 = (const float*)d_in[7];
  const float* tb0 = (const float*)d_in[8];
  const float* tw1 = (const float*)d_in[9];
  const float* tb1 = (const float*)d_in[10];
  const float* tw2 = (const float*)d_in[11];
  const float* tb2 = (const float*)d_in[12];

  // ---- workspace layout (~190 MB; w-plane buffers reused across the two MLPs) ----
  char* ws = (char*)d_ws;
  size_t off = 0;
  auto alloc = [&](size_t bytes) {
    void* p = ws + off;
    off += (bytes + 255) & ~(size_t)255;
    return p;
  };
  u16* xhi  = (u16*)alloc((size_t)NB * ND * 2);
  u16* xlo  = (u16*)alloc((size_t)NB * ND * 2);
  u16* w0hi = (u16*)alloc((size_t)NH * ND * 2);
  u16* w0lo = (u16*)alloc((size_t)NH * ND * 2);
  u16* w1hi = (u16*)alloc((size_t)NH * NH * 2);
  u16* w1lo = (u16*)alloc((size_t)NH * NH * 2);
  u16* w2hi = (u16*)alloc((size_t)ND * NH * 2);
  u16* w2lo = (u16*)alloc((size_t)ND * NH * 2);
  u16* h1hi = (u16*)alloc((size_t)NB * NH * 2);
  u16* h1lo = (u16*)alloc((size_t)NB * NH * 2);
  u16* h2hi = (u16*)alloc((size_t)NB * NH * 2);
  u16* h2lo = (u16*)alloc((size_t)NB * NH * 2);
  float* pm   = (float*)alloc((size_t)4 * NB * ND * 4);
  float* pa   = (float*)alloc((size_t)4 * NB * ND * 4);
  float* b0p  = (float*)alloc((size_t)NH * 4);
  float* b1p  = (float*)alloc((size_t)NH * 4);
  unsigned* ctrs = (unsigned*)alloc(256);   // 64 slots; init_ctrs zeroes ALL of them

  float* out_u = (float*)d_out;
  float* out_s = out_u + (long)NB * ND;

  constexpr int XB   = (NB * ND) / 256;                    // 4096
  constexpr int WSEG = (NH * ND) / 256 + 2 * (NH / 256);   // w0 + b0 + b1 = 1040

  init_ctrs<<<1, 64, 0, stream>>>(ctrs);

  auto run_mlp = [&](int phase, const float* w0, const float* b0, const float* w1,
                     const float* b1, const float* w2, float* part, bool is_tanh) {
    if (phase == 0)
      prep_small<0><<<XB + WSEG, 256, 0, stream>>>(x, w0, b0, b1, xhi, xlo,
                                                   w0hi, w0lo, b0p, b1p);
    else
      prep_small<1><<<WSEG, 256, 0, stream>>>(x, w0, b0, b1, xhi, xlo,
                                              w0hi, w0lo, b0p, b1p);
    prep_rows<<<NH + ND, 256, 0, stream>>>(w1, w2, w1hi, w1lo, w2hi, w2lo);
    dim3 g1(NH / 128, NB / 128, 1);
    if (is_tanh) {
      gemm_split<0, 1><<<g1, 256, 0, stream>>>(xhi, xlo, w0hi, w0lo, b0p,
                                               h1hi, h1lo, nullptr, NB, NH, ND, 0);
      gemm_l2_persist<0><<<1024, 256, 0, stream>>>(h1hi, h1lo, w1hi, w1lo, b1p,
                                                   h2hi, h2lo, ctrs + phase * 8);
    } else {
      gemm_split<1, 1><<<g1, 256, 0, stream>>>(xhi, xlo, w0hi, w0lo, b0p,
                                               h1hi, h1lo, nullptr, NB, NH, ND, 0);
      gemm_l2_persist<1><<<1024, 256, 0, stream>>>(h1hi, h1lo, w1hi, w1lo, b1p,
                                                   h2hi, h2lo, ctrs + phase * 8);
    }
    // L3: N=128, split-K=4 -> grid 64x4 = 256 blocks
    dim3 g3(1, NB / 128, 4);
    gemm_split<2, 0><<<g3, 256, 0, stream>>>(h2hi, h2lo, w2hi, w2lo, nullptr,
                                             nullptr, nullptr, part, NB, ND, NH,
                                             (NH / 4) / 32);
  };

  run_mlp(0, sw0, sb0, sw1, sb1, sw2, pm, true);   // s-MLP (tanh) -> m partials
  run_mlp(1, tw0, tb0, tw1, tb1, tw2, pa, false);  // t-MLP (relu) -> a partials

  finalize_kernel<<<NB / 4, 256, 0, stream>>>(x, pm, pa, sb2, tb2, out_u, out_s);
}